// Round 3
// baseline (363.895 us; speedup 1.0000x reference)
//
#include <hip/hip_runtime.h>
#include <hip/hip_bf16.h>
#include <stdint.h>

// GAT: N=4096, F_in=512, H=8, F_out=64.
// exp(lrelu(s_i+d_j)) = max(e^{s_i} e^{d_j}, e^{0.2 s_i} e^{0.2 d_j})  (exact)
// -> no per-pair exp/compare-chain, no online softmax, adjacency as bitmask.
// Round 3: in-block 4-way j-split + LDS reduce (32 waves/CU), max-trick P-build,
// decoupled s,d GEMV (s = X @ W^T a), lean 1-tile proj waves.

#define NN 4096
#define FIN 512
#define NH 8
#define FO 64

typedef __attribute__((ext_vector_type(8))) short bf16x8;
typedef __attribute__((ext_vector_type(4))) float f32x4;

__device__ __forceinline__ unsigned short f2bf(float f) {
  unsigned u = __float_as_uint(f);
  u += 0x7fffu + ((u >> 16) & 1u);   // RNE; finite inputs
  return (unsigned short)(u >> 16);
}

// ---------------- prep: adj->bitsT, X->bf16, W->WbT, wa = W^T a ----------------
__global__ __launch_bounds__(256) void prep_kernel(
    const float* __restrict__ X, const int* __restrict__ adj, const float* __restrict__ W,
    const float* __restrict__ a,
    unsigned short* __restrict__ Xb, unsigned short* __restrict__ WbT,
    unsigned* __restrict__ adjbitsT, unsigned short* __restrict__ WAb) {
  int bid = blockIdx.x, tid = threadIdx.x;
  if (bid < 2048) {                       // adj -> bit words, transposed [jt][r]
    int item = bid * 256 + tid;           // item = jt*4096 + r
    int jt = item >> 12, r = item & 4095;
    const int* p = adj + (size_t)r * NN + jt * 32;
    unsigned bits = 0;
#pragma unroll
    for (int b = 0; b < 32; b += 4) {
      int4 v = *(const int4*)(p + b);
      bits |= (unsigned)(v.x & 1) << b;
      bits |= (unsigned)(v.y & 1) << (b + 1);
      bits |= (unsigned)(v.z & 1) << (b + 2);
      bits |= (unsigned)(v.w & 1) << (b + 3);
    }
    adjbitsT[item] = bits;
  } else if (bid < 4096) {                // X -> bf16
    int item = (bid - 2048) * 256 + tid;
    float4 v = ((const float4*)X)[item];
    ushort4 o;
    o.x = f2bf(v.x); o.y = f2bf(v.y); o.z = f2bf(v.z); o.w = f2bf(v.w);
    ((ushort4*)Xb)[item] = o;
  } else if (bid < 5120) {                // W[h][k][o] -> WbT[h][o][k]
    int item = (bid - 4096) * 256 + tid;
    int h = item >> 15, rem = item & 32767, o = rem >> 9, k = rem & 511;
    WbT[item] = f2bf(W[h * (FIN * FO) + k * FO + o]);
  } else {                                // wa[t][k] = sum_o W[h][k][o] * a[h][which*64+o]
    int item = (bid - 5120) * 256 + tid;  // 8192 items: t = h*2+which, k
    int h = item >> 10, which = (item >> 9) & 1, k = item & 511;
    const float4* wp = (const float4*)(W + ((size_t)h * FIN + k) * FO);
    const float4* ap = (const float4*)(a + h * 128 + which * 64);
    float s = 0.f;
#pragma unroll
    for (int o4 = 0; o4 < 16; ++o4) {
      float4 w4 = wp[o4], a4 = ap[o4];
      s += w4.x * a4.x + w4.y * a4.y + w4.z * a4.z + w4.w * a4.w;
    }
    WAb[(h * 2 + which) * FIN + k] = f2bf(s);
  }
}

// ---------------- proj (+sd): Wh fragments, and s,d -> A,B,E1,E2 tables ------------
// D layout (16x16x32): col = lane&15, row = (lane>>4)*4 + reg   [m89]
__global__ __launch_bounds__(256, 8) void proj_sd_kernel(
    const unsigned short* __restrict__ Xb, const unsigned short* __restrict__ WbT,
    const unsigned short* __restrict__ WAb,
    unsigned short* __restrict__ Whfrag, float2* __restrict__ ABf,
    float* __restrict__ E1f, float* __restrict__ E2f) {
  int lane = threadIdx.x & 63, wave = threadIdx.x >> 6;
  int row16 = lane & 15, grp = lane >> 4;
  if (blockIdx.y == 8) {                  // sd: [s,d]x8 = X @ WA  (16 cols, K=512)
    if (blockIdx.x >= 64) return;
    int i0 = (blockIdx.x * 4 + wave) * 16;
    f32x4 acc = {0, 0, 0, 0};
    const unsigned short* xb = Xb + (size_t)(i0 + row16) * FIN + grp * 8;
    const unsigned short* wb = WAb + row16 * FIN + grp * 8;
#pragma unroll
    for (int k0 = 0; k0 < FIN; k0 += 32)
      acc = __builtin_amdgcn_mfma_f32_16x16x32_bf16(*(const bf16x8*)(xb + k0),
                                                    *(const bf16x8*)(wb + k0), acc, 0, 0, 0);
    int hh = row16 >> 1;
#pragma unroll
    for (int reg = 0; reg < 4; ++reg) {
      int rr = i0 + grp * 4 + reg;
      float v = acc[reg];
      if (row16 & 1) {                    // d -> col tables
        E1f[hh * NN + rr] = __expf(v);
        E2f[hh * NN + rr] = __expf(0.2f * v);
      } else {                            // s -> row tables
        ABf[hh * NN + rr] = make_float2(__expf(v), __expf(0.2f * v));
      }
    }
    return;
  }
  int h = blockIdx.y, cb = wave, i0 = blockIdx.x * 16;
  f32x4 acc = {0, 0, 0, 0};
  const unsigned short* xb = Xb + (size_t)(i0 + row16) * FIN + grp * 8;
  const unsigned short* wb = WbT + h * (FO * FIN) + (cb * 16 + row16) * FIN + grp * 8;
#pragma unroll
  for (int k0 = 0; k0 < FIN; k0 += 32)
    acc = __builtin_amdgcn_mfma_f32_16x16x32_bf16(*(const bf16x8*)(xb + k0),
                                                  *(const bf16x8*)(wb + k0), acc, 0, 0, 0);
  // Whfrag[h][jt][cb][l][e] = Wh[jt*32 + (l>>4)*8 + e][cb*16 + (l&15)]
  int jt = blockIdx.x >> 1, half = blockIdx.x & 1;
  int tl = (half * 2 + (grp >> 1)) * 16 + row16;
  int e0 = (grp & 1) * 4;
  ushort4 pk;
  pk.x = f2bf(acc[0]); pk.y = f2bf(acc[1]); pk.z = f2bf(acc[2]); pk.w = f2bf(acc[3]);
  *(ushort4*)(Whfrag + (((size_t)h * 128 + jt) * 4 + cb) * 512 + tl * 8 + e0) = pk;
}

// ---------------- gat: out = softmax_adj(e) @ Wh, 4-way j-split in block -----------
struct Frag {
  unsigned bw;
  float4 e1a, e1b, e2a, e2b;
  bf16x8 b0, b1, b2, b3;
};

__device__ __forceinline__ Frag ld_frag(const unsigned* __restrict__ bpT,
                                        const float* __restrict__ e1p,
                                        const float* __restrict__ e2p,
                                        const unsigned short* __restrict__ wfp, int jt) {
  Frag f;
  f.bw  = bpT[(size_t)jt * NN];
  f.e1a = *(const float4*)(e1p + jt * 32);
  f.e1b = *(const float4*)(e1p + jt * 32 + 4);
  f.e2a = *(const float4*)(e2p + jt * 32);
  f.e2b = *(const float4*)(e2p + jt * 32 + 4);
  const unsigned short* w = wfp + (size_t)jt * 2048;
  f.b0 = *(const bf16x8*)(w);
  f.b1 = *(const bf16x8*)(w + 512);
  f.b2 = *(const bf16x8*)(w + 1024);
  f.b3 = *(const bf16x8*)(w + 1536);
  return f;
}

__device__ __forceinline__ void gat_body(const Frag& f, int grp, float Ai, float Bi,
                                         const bf16x8& ones, f32x4& a0, f32x4& a1, f32x4& a2,
                                         f32x4& ad, f32x4& aden) {
  unsigned bb = (f.bw >> (grp * 8)) & 0xffu;
  float E1[8] = {f.e1a.x, f.e1a.y, f.e1a.z, f.e1a.w, f.e1b.x, f.e1b.y, f.e1b.z, f.e1b.w};
  float E2[8] = {f.e2a.x, f.e2a.y, f.e2a.z, f.e2a.w, f.e2b.x, f.e2b.y, f.e2b.z, f.e2b.w};
  bf16x8 af;
#pragma unroll
  for (int e = 0; e < 8; ++e) {
    float val = fmaxf(Ai * E1[e], Bi * E2[e]);      // = exp(lrelu(s+d)) exactly
    val = (bb & (1u << e)) ? val : 0.0f;
    __hip_bfloat16 hb = __float2bfloat16(val);
    af[e] = *reinterpret_cast<short*>(&hb);
  }
  a0   = __builtin_amdgcn_mfma_f32_16x16x32_bf16(af, f.b0, a0, 0, 0, 0);
  a1   = __builtin_amdgcn_mfma_f32_16x16x32_bf16(af, f.b1, a1, 0, 0, 0);
  a2   = __builtin_amdgcn_mfma_f32_16x16x32_bf16(af, f.b2, a2, 0, 0, 0);
  aden = __builtin_amdgcn_mfma_f32_16x16x32_bf16(af, ones, aden, 0, 0, 0);  // row-sum
  ad   = __builtin_amdgcn_mfma_f32_16x16x32_bf16(af, f.b3, ad, 0, 0, 0);
}

__global__ __launch_bounds__(512, 8) void gat_kernel(
    const unsigned* __restrict__ adjbitsT, const unsigned short* __restrict__ Whfrag,
    const float2* __restrict__ ABf, const float* __restrict__ E1f,
    const float* __restrict__ E2f, float* __restrict__ out) {
  __shared__ float red[6 * 64 * 20];      // 30 KB: 2 rt x 3 segs x 64 lanes x 20 floats
  int h = blockIdx.y;
  int lane = threadIdx.x & 63, wave = threadIdx.x >> 6;
  int row16 = lane & 15, grp = lane >> 4;
  int rt = wave >> 2, jseg = wave & 3;
  int i0 = (blockIdx.x * 2 + rt) * 16;
  int r = i0 + row16;
  float2 ab = ABf[h * NN + r];
  float Ai = ab.x, Bi = ab.y;

  bf16x8 ones;
#pragma unroll
  for (int e = 0; e < 8; ++e) ones[e] = (short)0x3F80;

  const unsigned* bpT = adjbitsT + r;
  const float* e1p = E1f + h * NN + grp * 8;
  const float* e2p = E2f + h * NN + grp * 8;
  const unsigned short* wfp = Whfrag + (size_t)h * 262144 + lane * 8;

  f32x4 a0 = {0,0,0,0}, a1 = {0,0,0,0}, a2 = {0,0,0,0}, ad = {0,0,0,0}, aden = {0,0,0,0};
  int jt0 = jseg * 32;
  Frag cur = ld_frag(bpT, e1p, e2p, wfp, jt0);
#pragma unroll 2
  for (int t = 1; t < 32; ++t) {
    Frag nxt = ld_frag(bpT, e1p, e2p, wfp, jt0 + t);   // depth-1 prefetch
    gat_body(cur, grp, Ai, Bi, ones, a0, a1, a2, ad, aden);
    cur = nxt;
  }
  gat_body(cur, grp, Ai, Bi, ones, a0, a1, a2, ad, aden);

  if (jseg != 0) {
    float* q = &red[((rt * 3 + (jseg - 1)) * 64 + lane) * 20];
    *(f32x4*)(q +  0) = a0;
    *(f32x4*)(q +  4) = a1;
    *(f32x4*)(q +  8) = a2;
    *(f32x4*)(q + 12) = ad;
    *(f32x4*)(q + 16) = aden;
  }
  __syncthreads();
  if (jseg == 0) {
#pragma unroll
    for (int s = 0; s < 3; ++s) {
      const float* q = &red[((rt * 3 + s) * 64 + lane) * 20];
      a0   += *(const f32x4*)(q +  0);
      a1   += *(const f32x4*)(q +  4);
      a2   += *(const f32x4*)(q +  8);
      ad   += *(const f32x4*)(q + 12);
      aden += *(const f32x4*)(q + 16);
    }
#pragma unroll
    for (int reg = 0; reg < 4; ++reg) {
      float inv = 1.0f / aden[reg];
      int row = i0 + grp * 4 + reg;
      float* op = out + (size_t)row * (NH * FO) + h * FO + row16;
      op[0]  = a0[reg] * inv;
      op[16] = a1[reg] * inv;
      op[32] = a2[reg] * inv;
      op[48] = ad[reg] * inv;
    }
  }
}

extern "C" void kernel_launch(void* const* d_in, const int* in_sizes, int n_in,
                              void* d_out, int out_size, void* d_ws, size_t ws_size,
                              hipStream_t stream) {
  const float* X  = (const float*)d_in[0];
  const int* adj  = (const int*)d_in[1];
  const float* W  = (const float*)d_in[2];
  const float* a  = (const float*)d_in[3];
  float* out = (float*)d_out;
  char* ws = (char*)d_ws;

  unsigned short* Xb     = (unsigned short*)(ws + 0);          // 4 MB
  unsigned short* WbT    = (unsigned short*)(ws + 4194304);    // 512 KB
  unsigned* adjbitsT     = (unsigned*)(ws + 4718592);          // 2 MB
  unsigned short* Whfrag = (unsigned short*)(ws + 6815744);    // 4 MB
  unsigned short* WAb    = (unsigned short*)(ws + 11010048);   // 16 KB
  float2* ABf            = (float2*)(ws + 11026432);           // 256 KB
  float* E1f             = (float*)(ws + 11288576);            // 128 KB
  float* E2f             = (float*)(ws + 11419648);            // 128 KB (total ~11.5 MB)

  prep_kernel<<<5152, 256, 0, stream>>>(X, adj, W, a, Xb, WbT, adjbitsT, WAb);
  proj_sd_kernel<<<dim3(256, 9), 256, 0, stream>>>(Xb, WbT, WAb, Whfrag, ABf, E1f, E2f);
  gat_kernel<<<dim3(128, 8), 512, 0, stream>>>(adjbitsT, Whfrag, ABf, E1f, E2f, out);
}

// Round 4
// 118.945 us; speedup vs baseline: 3.0594x; 3.0594x over previous
//
#include <hip/hip_runtime.h>
#include <hip/hip_bf16.h>
#include <stdint.h>

// GAT: N=4096, F_in=512, H=8, F_out=64.
// exp(lrelu(s_i+d_j)) = max(e^{s_i} e^{d_j}, e^{0.2 s_i} e^{0.2 d_j})  (exact)
// -> no per-pair exp, no online softmax, adjacency as bitmask.
// Round 4: fix round-3 spill disaster (launch_bounds (512,4), VGPR budget 128),
// block = 4 row-tiles x 2 j-segments (halves L2 Whfrag traffic vs 2x4).

#define NN 4096
#define FIN 512
#define NH 8
#define FO 64

typedef __attribute__((ext_vector_type(8))) short bf16x8;
typedef __attribute__((ext_vector_type(4))) float f32x4;

__device__ __forceinline__ unsigned short f2bf(float f) {
  unsigned u = __float_as_uint(f);
  u += 0x7fffu + ((u >> 16) & 1u);   // RNE; finite inputs
  return (unsigned short)(u >> 16);
}

// ---------------- prep: adj->bitsT, X->bf16, W->WbT, wa = W^T a ----------------
__global__ __launch_bounds__(256) void prep_kernel(
    const float* __restrict__ X, const int* __restrict__ adj, const float* __restrict__ W,
    const float* __restrict__ a,
    unsigned short* __restrict__ Xb, unsigned short* __restrict__ WbT,
    unsigned* __restrict__ adjbitsT, unsigned short* __restrict__ WAb) {
  int bid = blockIdx.x, tid = threadIdx.x;
  if (bid < 2048) {                       // adj -> bit words, transposed [jt][r]
    int item = bid * 256 + tid;           // item = jt*4096 + r
    int jt = item >> 12, r = item & 4095;
    const int* p = adj + (size_t)r * NN + jt * 32;
    unsigned bits = 0;
#pragma unroll
    for (int b = 0; b < 32; b += 4) {
      int4 v = *(const int4*)(p + b);
      bits |= (unsigned)(v.x & 1) << b;
      bits |= (unsigned)(v.y & 1) << (b + 1);
      bits |= (unsigned)(v.z & 1) << (b + 2);
      bits |= (unsigned)(v.w & 1) << (b + 3);
    }
    adjbitsT[item] = bits;
  } else if (bid < 4096) {                // X -> bf16
    int item = (bid - 2048) * 256 + tid;
    float4 v = ((const float4*)X)[item];
    ushort4 o;
    o.x = f2bf(v.x); o.y = f2bf(v.y); o.z = f2bf(v.z); o.w = f2bf(v.w);
    ((ushort4*)Xb)[item] = o;
  } else if (bid < 5120) {                // W[h][k][o] -> WbT[h][o][k]
    int item = (bid - 4096) * 256 + tid;
    int h = item >> 15, rem = item & 32767, o = rem >> 9, k = rem & 511;
    WbT[item] = f2bf(W[h * (FIN * FO) + k * FO + o]);
  } else {                                // wa[t][k] = sum_o W[h][k][o] * a[h][which*64+o]
    int item = (bid - 5120) * 256 + tid;  // 8192 items: t = h*2+which, k
    int h = item >> 10, which = (item >> 9) & 1, k = item & 511;
    const float4* wp = (const float4*)(W + ((size_t)h * FIN + k) * FO);
    const float4* ap = (const float4*)(a + h * 128 + which * 64);
    float s = 0.f;
#pragma unroll
    for (int o4 = 0; o4 < 16; ++o4) {
      float4 w4 = wp[o4], a4 = ap[o4];
      s += w4.x * a4.x + w4.y * a4.y + w4.z * a4.z + w4.w * a4.w;
    }
    WAb[(h * 2 + which) * FIN + k] = f2bf(s);
  }
}

// ---------------- proj (+sd): Wh fragments, and s,d -> A,B,E1,E2 tables ------------
// D layout (16x16x32): col = lane&15, row = (lane>>4)*4 + reg   [m89]
__global__ __launch_bounds__(256, 8) void proj_sd_kernel(
    const unsigned short* __restrict__ Xb, const unsigned short* __restrict__ WbT,
    const unsigned short* __restrict__ WAb,
    unsigned short* __restrict__ Whfrag, float2* __restrict__ ABf,
    float* __restrict__ E1f, float* __restrict__ E2f) {
  int lane = threadIdx.x & 63, wave = threadIdx.x >> 6;
  int row16 = lane & 15, grp = lane >> 4;
  if (blockIdx.y == 8) {                  // sd: [s,d]x8 = X @ WA  (16 cols, K=512)
    if (blockIdx.x >= 64) return;
    int i0 = (blockIdx.x * 4 + wave) * 16;
    f32x4 acc = {0, 0, 0, 0};
    const unsigned short* xb = Xb + (size_t)(i0 + row16) * FIN + grp * 8;
    const unsigned short* wb = WAb + row16 * FIN + grp * 8;
#pragma unroll
    for (int k0 = 0; k0 < FIN; k0 += 32)
      acc = __builtin_amdgcn_mfma_f32_16x16x32_bf16(*(const bf16x8*)(xb + k0),
                                                    *(const bf16x8*)(wb + k0), acc, 0, 0, 0);
    int hh = row16 >> 1;
#pragma unroll
    for (int reg = 0; reg < 4; ++reg) {
      int rr = i0 + grp * 4 + reg;
      float v = acc[reg];
      if (row16 & 1) {                    // d -> col tables
        E1f[hh * NN + rr] = __expf(v);
        E2f[hh * NN + rr] = __expf(0.2f * v);
      } else {                            // s -> row tables
        ABf[hh * NN + rr] = make_float2(__expf(v), __expf(0.2f * v));
      }
    }
    return;
  }
  int h = blockIdx.y, cb = wave, i0 = blockIdx.x * 16;
  f32x4 acc = {0, 0, 0, 0};
  const unsigned short* xb = Xb + (size_t)(i0 + row16) * FIN + grp * 8;
  const unsigned short* wb = WbT + h * (FO * FIN) + (cb * 16 + row16) * FIN + grp * 8;
#pragma unroll
  for (int k0 = 0; k0 < FIN; k0 += 32)
    acc = __builtin_amdgcn_mfma_f32_16x16x32_bf16(*(const bf16x8*)(xb + k0),
                                                  *(const bf16x8*)(wb + k0), acc, 0, 0, 0);
  // Whfrag[h][jt][cb][l][e] = Wh[jt*32 + (l>>4)*8 + e][cb*16 + (l&15)]
  int jt = blockIdx.x >> 1, half = blockIdx.x & 1;
  int tl = (half * 2 + (grp >> 1)) * 16 + row16;
  int e0 = (grp & 1) * 4;
  ushort4 pk;
  pk.x = f2bf(acc[0]); pk.y = f2bf(acc[1]); pk.z = f2bf(acc[2]); pk.w = f2bf(acc[3]);
  *(ushort4*)(Whfrag + (((size_t)h * 128 + jt) * 4 + cb) * 512 + tl * 8 + e0) = pk;
}

// ---------------- gat: out = softmax_adj(e) @ Wh, 4 rt x 2 jseg per block ----------
struct Frag {
  unsigned bw;
  float4 e1a, e1b, e2a, e2b;
  bf16x8 b0, b1, b2, b3;
};

__device__ __forceinline__ Frag ld_frag(const unsigned* __restrict__ bpT,
                                        const float* __restrict__ e1p,
                                        const float* __restrict__ e2p,
                                        const unsigned short* __restrict__ wfp, int jt) {
  Frag f;
  f.bw  = bpT[(size_t)jt * NN];
  f.e1a = *(const float4*)(e1p + jt * 32);
  f.e1b = *(const float4*)(e1p + jt * 32 + 4);
  f.e2a = *(const float4*)(e2p + jt * 32);
  f.e2b = *(const float4*)(e2p + jt * 32 + 4);
  const unsigned short* w = wfp + (size_t)jt * 2048;
  f.b0 = *(const bf16x8*)(w);
  f.b1 = *(const bf16x8*)(w + 512);
  f.b2 = *(const bf16x8*)(w + 1024);
  f.b3 = *(const bf16x8*)(w + 1536);
  return f;
}

__device__ __forceinline__ void gat_body(const Frag& f, int grp, float Ai, float Bi,
                                         const bf16x8& ones, f32x4& a0, f32x4& a1, f32x4& a2,
                                         f32x4& ad, f32x4& aden) {
  unsigned bb = (f.bw >> (grp * 8)) & 0xffu;
  float E1[8] = {f.e1a.x, f.e1a.y, f.e1a.z, f.e1a.w, f.e1b.x, f.e1b.y, f.e1b.z, f.e1b.w};
  float E2[8] = {f.e2a.x, f.e2a.y, f.e2a.z, f.e2a.w, f.e2b.x, f.e2b.y, f.e2b.z, f.e2b.w};
  bf16x8 af;
#pragma unroll
  for (int e = 0; e < 8; ++e) {
    float val = fmaxf(Ai * E1[e], Bi * E2[e]);      // = exp(lrelu(s+d)) exactly
    val = (bb & (1u << e)) ? val : 0.0f;
    __hip_bfloat16 hb = __float2bfloat16(val);
    af[e] = *reinterpret_cast<short*>(&hb);
  }
  a0   = __builtin_amdgcn_mfma_f32_16x16x32_bf16(af, f.b0, a0, 0, 0, 0);
  a1   = __builtin_amdgcn_mfma_f32_16x16x32_bf16(af, f.b1, a1, 0, 0, 0);
  a2   = __builtin_amdgcn_mfma_f32_16x16x32_bf16(af, f.b2, a2, 0, 0, 0);
  aden = __builtin_amdgcn_mfma_f32_16x16x32_bf16(af, ones, aden, 0, 0, 0);  // row-sum
  ad   = __builtin_amdgcn_mfma_f32_16x16x32_bf16(af, f.b3, ad, 0, 0, 0);
}

__global__ __launch_bounds__(512, 4) void gat_kernel(
    const unsigned* __restrict__ adjbitsT, const unsigned short* __restrict__ Whfrag,
    const float2* __restrict__ ABf, const float* __restrict__ E1f,
    const float* __restrict__ E2f, float* __restrict__ out) {
  __shared__ float red[4 * 64 * 20];      // 20 KB: 4 rt x 64 lanes x 20 floats
  int h = blockIdx.y;
  int lane = threadIdx.x & 63, wave = threadIdx.x >> 6;
  int row16 = lane & 15, grp = lane >> 4;
  int rt = wave >> 1, jseg = wave & 1;
  int i0 = blockIdx.x * 64 + rt * 16;
  int r = i0 + row16;
  float2 ab = ABf[h * NN + r];
  float Ai = ab.x, Bi = ab.y;

  bf16x8 ones;
#pragma unroll
  for (int e = 0; e < 8; ++e) ones[e] = (short)0x3F80;

  const unsigned* bpT = adjbitsT + r;
  const float* e1p = E1f + h * NN + grp * 8;
  const float* e2p = E2f + h * NN + grp * 8;
  const unsigned short* wfp = Whfrag + (size_t)h * 262144 + lane * 8;

  f32x4 a0 = {0,0,0,0}, a1 = {0,0,0,0}, a2 = {0,0,0,0}, ad = {0,0,0,0}, aden = {0,0,0,0};
  int jt0 = jseg * 64;
  Frag cur = ld_frag(bpT, e1p, e2p, wfp, jt0);
#pragma unroll 2
  for (int t = 1; t < 64; ++t) {
    Frag nxt = ld_frag(bpT, e1p, e2p, wfp, jt0 + t);   // depth-1 prefetch
    gat_body(cur, grp, Ai, Bi, ones, a0, a1, a2, ad, aden);
    cur = nxt;
  }
  gat_body(cur, grp, Ai, Bi, ones, a0, a1, a2, ad, aden);

  if (jseg == 1) {
    float* q = &red[(rt * 64 + lane) * 20];
    *(f32x4*)(q +  0) = a0;
    *(f32x4*)(q +  4) = a1;
    *(f32x4*)(q +  8) = a2;
    *(f32x4*)(q + 12) = ad;
    *(f32x4*)(q + 16) = aden;
  }
  __syncthreads();
  if (jseg == 0) {
    const float* q = &red[(rt * 64 + lane) * 20];
    a0   += *(const f32x4*)(q +  0);
    a1   += *(const f32x4*)(q +  4);
    a2   += *(const f32x4*)(q +  8);
    ad   += *(const f32x4*)(q + 12);
    aden += *(const f32x4*)(q + 16);
#pragma unroll
    for (int reg = 0; reg < 4; ++reg) {
      float inv = 1.0f / aden[reg];
      int row = i0 + grp * 4 + reg;
      float* op = out + (size_t)row * (NH * FO) + h * FO + row16;
      op[0]  = a0[reg] * inv;
      op[16] = a1[reg] * inv;
      op[32] = a2[reg] * inv;
      op[48] = ad[reg] * inv;
    }
  }
}

extern "C" void kernel_launch(void* const* d_in, const int* in_sizes, int n_in,
                              void* d_out, int out_size, void* d_ws, size_t ws_size,
                              hipStream_t stream) {
  const float* X  = (const float*)d_in[0];
  const int* adj  = (const int*)d_in[1];
  const float* W  = (const float*)d_in[2];
  const float* a  = (const float*)d_in[3];
  float* out = (float*)d_out;
  char* ws = (char*)d_ws;

  unsigned short* Xb     = (unsigned short*)(ws + 0);          // 4 MB
  unsigned short* WbT    = (unsigned short*)(ws + 4194304);    // 512 KB
  unsigned* adjbitsT     = (unsigned*)(ws + 4718592);          // 2 MB
  unsigned short* Whfrag = (unsigned short*)(ws + 6815744);    // 4 MB
  unsigned short* WAb    = (unsigned short*)(ws + 11010048);   // 16 KB
  float2* ABf            = (float2*)(ws + 11026432);           // 256 KB
  float* E1f             = (float*)(ws + 11288576);            // 128 KB
  float* E2f             = (float*)(ws + 11419648);            // 128 KB (total ~11.5 MB)

  prep_kernel<<<5152, 256, 0, stream>>>(X, adj, W, a, Xb, WbT, adjbitsT, WAb);
  proj_sd_kernel<<<dim3(256, 9), 256, 0, stream>>>(Xb, WbT, WAb, Whfrag, ABf, E1f, E2f);
  gat_kernel<<<dim3(64, 8), 512, 0, stream>>>(adjbitsT, Whfrag, ABf, E1f, E2f, out);
}

// Round 5
// 89.116 us; speedup vs baseline: 4.0834x; 1.3347x over previous
//
#include <hip/hip_runtime.h>
#include <hip/hip_bf16.h>
#include <stdint.h>

// GAT: N=4096, F_in=512, H=8, F_out=64.
// exp(lrelu(s_i+d_j)) = max(e^{s_i} e^{d_j}, e^{0.2 s_i} e^{0.2 d_j})  (exact)
// Round 5: gat as 2-phase LDS pipeline (global_load_lds double-buffer, T3-minimum),
// interleaved E12 table, proj back to 4-acc waves. Block = 4 rt x 2 jseg, 72KB LDS.

#define NN 4096
#define FIN 512
#define NH 8
#define FO 64

typedef __attribute__((ext_vector_type(8))) short bf16x8;
typedef __attribute__((ext_vector_type(4))) float f32x4;

#define GLOAD_LDS16(g, l)                                                          \
  __builtin_amdgcn_global_load_lds((__attribute__((address_space(1))) const void*)(g), \
                                   (__attribute__((address_space(3))) void*)(l), 16, 0, 0)
#define GLOAD_LDS4(g, l)                                                           \
  __builtin_amdgcn_global_load_lds((__attribute__((address_space(1))) const void*)(g), \
                                   (__attribute__((address_space(3))) void*)(l), 4, 0, 0)

__device__ __forceinline__ unsigned short f2bf(float f) {
  unsigned u = __float_as_uint(f);
  u += 0x7fffu + ((u >> 16) & 1u);   // RNE; finite inputs
  return (unsigned short)(u >> 16);
}

// ---------------- prep: adj->bitsT, X->bf16, W->WbT, wa = W^T a ----------------
__global__ __launch_bounds__(256) void prep_kernel(
    const float* __restrict__ X, const int* __restrict__ adj, const float* __restrict__ W,
    const float* __restrict__ a,
    unsigned short* __restrict__ Xb, unsigned short* __restrict__ WbT,
    unsigned* __restrict__ adjbitsT, unsigned short* __restrict__ WAb) {
  int bid = blockIdx.x, tid = threadIdx.x;
  if (bid < 2048) {                       // adj -> bit words, transposed [jt][r]
    int item = bid * 256 + tid;           // item = jt*4096 + r
    int jt = item >> 12, r = item & 4095;
    const int* p = adj + (size_t)r * NN + jt * 32;
    unsigned bits = 0;
#pragma unroll
    for (int b = 0; b < 32; b += 4) {
      int4 v = *(const int4*)(p + b);
      bits |= (unsigned)(v.x & 1) << b;
      bits |= (unsigned)(v.y & 1) << (b + 1);
      bits |= (unsigned)(v.z & 1) << (b + 2);
      bits |= (unsigned)(v.w & 1) << (b + 3);
    }
    adjbitsT[item] = bits;
  } else if (bid < 4096) {                // X -> bf16
    int item = (bid - 2048) * 256 + tid;
    float4 v = ((const float4*)X)[item];
    ushort4 o;
    o.x = f2bf(v.x); o.y = f2bf(v.y); o.z = f2bf(v.z); o.w = f2bf(v.w);
    ((ushort4*)Xb)[item] = o;
  } else if (bid < 5120) {                // W[h][k][o] -> WbT[h][o][k]
    int item = (bid - 4096) * 256 + tid;
    int h = item >> 15, rem = item & 32767, o = rem >> 9, k = rem & 511;
    WbT[item] = f2bf(W[h * (FIN * FO) + k * FO + o]);
  } else {                                // wa[t][k] = sum_o W[h][k][o] * a[h][which*64+o]
    int item = (bid - 5120) * 256 + tid;  // 8192 items: t = h*2+which, k
    int h = item >> 10, which = (item >> 9) & 1, k = item & 511;
    const float4* wp = (const float4*)(W + ((size_t)h * FIN + k) * FO);
    const float4* ap = (const float4*)(a + h * 128 + which * 64);
    float s = 0.f;
#pragma unroll
    for (int o4 = 0; o4 < 16; ++o4) {
      float4 w4 = wp[o4], a4 = ap[o4];
      s += w4.x * a4.x + w4.y * a4.y + w4.z * a4.z + w4.w * a4.w;
    }
    WAb[(h * 2 + which) * FIN + k] = f2bf(s);
  }
}

// ---------------- proj (+sd): Wh fragments (4-acc waves), s,d -> AB / E12 ----------
// D layout (16x16x32): col = lane&15, row = (lane>>4)*4 + reg   [m89]
__global__ __launch_bounds__(256, 4) void proj_sd_kernel(
    const unsigned short* __restrict__ Xb, const unsigned short* __restrict__ WbT,
    const unsigned short* __restrict__ WAb,
    unsigned short* __restrict__ Whfrag, float2* __restrict__ ABf,
    float2* __restrict__ E12f) {
  int lane = threadIdx.x & 63, wave = threadIdx.x >> 6;
  int row16 = lane & 15, grp = lane >> 4;
  if (blockIdx.y == 8) {                  // sd: [s,d]x8 = X @ WA  (16 cols, K=512)
    int i0 = (blockIdx.x * 4 + wave) * 16;
    f32x4 acc = {0, 0, 0, 0};
    const unsigned short* xb = Xb + (size_t)(i0 + row16) * FIN + grp * 8;
    const unsigned short* wb = WAb + row16 * FIN + grp * 8;
#pragma unroll
    for (int k0 = 0; k0 < FIN; k0 += 32)
      acc = __builtin_amdgcn_mfma_f32_16x16x32_bf16(*(const bf16x8*)(xb + k0),
                                                    *(const bf16x8*)(wb + k0), acc, 0, 0, 0);
    int hh = row16 >> 1;
#pragma unroll
    for (int reg = 0; reg < 4; ++reg) {
      int rr = i0 + grp * 4 + reg;
      float v = acc[reg];
      if (row16 & 1) {                    // d -> col tables (interleaved e^d, e^{0.2d})
        E12f[hh * NN + rr] = make_float2(__expf(v), __expf(0.2f * v));
      } else {                            // s -> row tables
        ABf[hh * NN + rr] = make_float2(__expf(v), __expf(0.2f * v));
      }
    }
    return;
  }
  int h = blockIdx.y;
  int i0 = blockIdx.x * 64 + wave * 16;
  f32x4 acc[4] = {{0,0,0,0},{0,0,0,0},{0,0,0,0},{0,0,0,0}};
  const unsigned short* xb = Xb + (size_t)(i0 + row16) * FIN + grp * 8;
  const unsigned short* wb = WbT + h * (FO * FIN) + row16 * FIN + grp * 8;
#pragma unroll 4
  for (int k0 = 0; k0 < FIN; k0 += 32) {
    bf16x8 af = *(const bf16x8*)(xb + k0);
#pragma unroll
    for (int cb = 0; cb < 4; ++cb)
      acc[cb] = __builtin_amdgcn_mfma_f32_16x16x32_bf16(
          af, *(const bf16x8*)(wb + cb * 16 * FIN + k0), acc[cb], 0, 0, 0);
  }
  // Whfrag[h][jt][cb][l][e] = Wh[jt*32 + (l>>4)*8 + e][cb*16 + (l&15)]
  int jt = i0 >> 5;
  int kk0 = (i0 & 31) + grp * 4;
  int tl = (kk0 >> 3) * 16 + row16;
  int e0 = kk0 & 7;
#pragma unroll
  for (int cb = 0; cb < 4; ++cb) {
    ushort4 pk;
    pk.x = f2bf(acc[cb][0]); pk.y = f2bf(acc[cb][1]);
    pk.z = f2bf(acc[cb][2]); pk.w = f2bf(acc[cb][3]);
    *(ushort4*)(Whfrag + (((size_t)h * 128 + jt) * 4 + cb) * 512 + tl * 8 + e0) = pk;
  }
}

// ---------------- gat: 2-phase LDS pipeline, 4 rt x 2 jseg per block ----------
// LDS per (jseg,buf) segment: [B 16384 | E12 1024 | adj 1024] = 18432 B; x4 = 72 KB
#define SEGB 18432
#define E_OFF 16384
#define A_OFF 17408
#define PH 4          // j-tiles per phase
#define NPHASE 16     // 64 jt per jseg

__global__ __launch_bounds__(512, 4) void gat_kernel(
    const unsigned* __restrict__ adjbitsT, const unsigned short* __restrict__ Whfrag,
    const float2* __restrict__ ABf, const float2* __restrict__ E12f,
    float* __restrict__ out) {
  __shared__ char lds[4 * SEGB];
  int h = blockIdx.y;
  int lane = threadIdx.x & 63, wave = threadIdx.x >> 6;
  int row16 = lane & 15, grp = lane >> 4;
  int rt = wave >> 1, jseg = wave & 1;
  int r0 = blockIdx.x * 64;
  int i0 = r0 + rt * 16;
  int r = i0 + row16;
  float2 ab = ABf[h * NN + r];
  float Ai = ab.x, Bi = ab.y;

  bf16x8 ones;
#pragma unroll
  for (int e = 0; e < 8; ++e) ones[e] = (short)0x3F80;

  const unsigned short* wsrc = Whfrag + (size_t)h * 262144 + lane * 8;
  const float2* esrc = E12f + h * NN + lane * 2;

  f32x4 a0 = {0,0,0,0}, a1 = {0,0,0,0}, a2 = {0,0,0,0}, ad = {0,0,0,0}, aden = {0,0,0,0};

  // ---- stage phase p into buffer buf (each wave stages jt_local == rt) ----
  auto stage = [&](int buf, int p) {
    int jt = jseg * 64 + p * PH + rt;
    char* base = lds + (jseg * 2 + buf) * SEGB;
    const unsigned short* bs = wsrc + (size_t)jt * 2048;
    char* bd = base + rt * 4096;
    GLOAD_LDS16(bs, bd);
    GLOAD_LDS16(bs + 512, bd + 1024);
    GLOAD_LDS16(bs + 1024, bd + 2048);
    GLOAD_LDS16(bs + 1536, bd + 3072);
    GLOAD_LDS4(adjbitsT + (size_t)jt * NN + r0 + lane, base + A_OFF + rt * 256);
    if (rt == 0)
      GLOAD_LDS16(esrc + (size_t)(jseg * 64 + p * PH) * 32, base + E_OFF);
  };

  // ---- compute one phase from buffer buf ----
  auto compute = [&](int buf) {
    char* base = lds + (jseg * 2 + buf) * SEGB;
#pragma unroll
    for (int t = 0; t < PH; ++t) {
      unsigned bw = *(const unsigned*)(base + A_OFF + t * 256 + (rt * 16 + row16) * 4);
      unsigned bb = (bw >> (grp * 8)) & 0xffu;
      const f32x4* ep = (const f32x4*)(base + E_OFF + t * 256 + grp * 64);
      f32x4 ev0 = ep[0], ev1 = ep[1], ev2 = ep[2], ev3 = ep[3];  // {e1,e2} pairs
      const char* bbase = base + t * 4096 + lane * 16;
      bf16x8 b0 = *(const bf16x8*)(bbase);
      bf16x8 b1 = *(const bf16x8*)(bbase + 1024);
      bf16x8 b2 = *(const bf16x8*)(bbase + 2048);
      bf16x8 b3 = *(const bf16x8*)(bbase + 3072);
      float v[8];
      v[0] = fmaxf(Ai * ev0[0], Bi * ev0[1]);
      v[1] = fmaxf(Ai * ev0[2], Bi * ev0[3]);
      v[2] = fmaxf(Ai * ev1[0], Bi * ev1[1]);
      v[3] = fmaxf(Ai * ev1[2], Bi * ev1[3]);
      v[4] = fmaxf(Ai * ev2[0], Bi * ev2[1]);
      v[5] = fmaxf(Ai * ev2[2], Bi * ev2[3]);
      v[6] = fmaxf(Ai * ev3[0], Bi * ev3[1]);
      v[7] = fmaxf(Ai * ev3[2], Bi * ev3[3]);
      bf16x8 af;
#pragma unroll
      for (int e = 0; e < 8; ++e) {
        float val = (bb & (1u << e)) ? v[e] : 0.0f;
        __hip_bfloat16 hb = __float2bfloat16(val);
        af[e] = *reinterpret_cast<short*>(&hb);
      }
      a0   = __builtin_amdgcn_mfma_f32_16x16x32_bf16(af, b0, a0, 0, 0, 0);
      a1   = __builtin_amdgcn_mfma_f32_16x16x32_bf16(af, b1, a1, 0, 0, 0);
      a2   = __builtin_amdgcn_mfma_f32_16x16x32_bf16(af, b2, a2, 0, 0, 0);
      aden = __builtin_amdgcn_mfma_f32_16x16x32_bf16(af, ones, aden, 0, 0, 0);
      ad   = __builtin_amdgcn_mfma_f32_16x16x32_bf16(af, b3, ad, 0, 0, 0);
    }
  };

  stage(0, 0);
  __syncthreads();                       // drains vmcnt -> phase 0 ready
  int b = 0;
#pragma unroll 1
  for (int p = 0; p < NPHASE; ++p) {
    if (p < NPHASE - 1) stage(b ^ 1, p + 1);   // async into other buffer
    compute(b);
    __syncthreads();                     // staged loads landed under compute
    b ^= 1;
  }

  // ---- cross-jseg reduction (reuse LDS) + normalize + store ----
  float* red = (float*)lds;
  if (jseg == 1) {
    float* q = red + (rt * 64 + lane) * 20;
    *(f32x4*)(q +  0) = a0;
    *(f32x4*)(q +  4) = a1;
    *(f32x4*)(q +  8) = a2;
    *(f32x4*)(q + 12) = ad;
    *(f32x4*)(q + 16) = aden;
  }
  __syncthreads();
  if (jseg == 0) {
    const float* q = red + (rt * 64 + lane) * 20;
    a0   += *(const f32x4*)(q +  0);
    a1   += *(const f32x4*)(q +  4);
    a2   += *(const f32x4*)(q +  8);
    ad   += *(const f32x4*)(q + 12);
    aden += *(const f32x4*)(q + 16);
#pragma unroll
    for (int reg = 0; reg < 4; ++reg) {
      float inv = 1.0f / aden[reg];
      int row = i0 + grp * 4 + reg;
      float* op = out + (size_t)row * (NH * FO) + h * FO + row16;
      op[0]  = a0[reg] * inv;
      op[16] = a1[reg] * inv;
      op[32] = a2[reg] * inv;
      op[48] = ad[reg] * inv;
    }
  }
}

extern "C" void kernel_launch(void* const* d_in, const int* in_sizes, int n_in,
                              void* d_out, int out_size, void* d_ws, size_t ws_size,
                              hipStream_t stream) {
  const float* X  = (const float*)d_in[0];
  const int* adj  = (const int*)d_in[1];
  const float* W  = (const float*)d_in[2];
  const float* a  = (const float*)d_in[3];
  float* out = (float*)d_out;
  char* ws = (char*)d_ws;

  unsigned short* Xb     = (unsigned short*)(ws + 0);          // 4 MB
  unsigned short* WbT    = (unsigned short*)(ws + 4194304);    // 512 KB
  unsigned* adjbitsT     = (unsigned*)(ws + 4718592);          // 2 MB
  unsigned short* Whfrag = (unsigned short*)(ws + 6815744);    // 4 MB
  unsigned short* WAb    = (unsigned short*)(ws + 11010048);   // 16 KB
  float2* ABf            = (float2*)(ws + 11026432);           // 256 KB
  float2* E12f           = (float2*)(ws + 11288576);           // 256 KB (total ~11.5 MB)

  prep_kernel<<<5152, 256, 0, stream>>>(X, adj, W, a, Xb, WbT, adjbitsT, WAb);
  proj_sd_kernel<<<dim3(64, 9), 256, 0, stream>>>(Xb, WbT, WAb, Whfrag, ABf, E12f);
  gat_kernel<<<dim3(64, 8), 512, 0, stream>>>(adjbitsT, Whfrag, ABf, E12f, out);
}

// Round 7
// 82.031 us; speedup vs baseline: 4.4361x; 1.0864x over previous
//
#include <hip/hip_runtime.h>
#include <stdint.h>

// GAT: N=4096, F_in=512, H=8, F_out=64.
// exp(lrelu(s_i+d_j)) = max(e^{s_i} e^{d_j}, e^{0.2 s_i} e^{0.2 d_j})  (exact)
// Round 7: round-6 fp16 plan, compile-fixed: clang-native _Float16 vectors
// (v_pk_mul_f16 / v_pk_max_f16 via elementwise ops), no fp16/bf16 header intrinsics.
// Mask folded in as fp16 exponent-trick multiply (bit<<14 = 2.0, A/B pre-halved).
// PH=2 -> 36KB LDS -> 4 blocks/CU (32 waves/CU).

#define NN 4096
#define FIN 512
#define NH 8
#define FO 64

typedef _Float16 f16x8 __attribute__((ext_vector_type(8)));
typedef _Float16 f16x2 __attribute__((ext_vector_type(2)));
typedef __attribute__((ext_vector_type(4))) float f32x4;

union H8 { f16x8 v; f16x2 p[4]; unsigned u[4]; };
union U2 { unsigned u; f16x2 v; };

#define GLOAD_LDS16(g, l)                                                          \
  __builtin_amdgcn_global_load_lds((__attribute__((address_space(1))) const void*)(g), \
                                   (__attribute__((address_space(3))) void*)(l), 16, 0, 0)
#define GLOAD_LDS4(g, l)                                                           \
  __builtin_amdgcn_global_load_lds((__attribute__((address_space(1))) const void*)(g), \
                                   (__attribute__((address_space(3))) void*)(l), 4, 0, 0)

__device__ __forceinline__ unsigned short f2h(float f) {
  _Float16 h = (_Float16)f;               // RNE
  return __builtin_bit_cast(unsigned short, h);
}

// ---------------- prep: adj->bitsT, X->fp16, W->WbT(fp16), wa = W^T a ----------------
__global__ __launch_bounds__(256) void prep_kernel(
    const float* __restrict__ X, const int* __restrict__ adj, const float* __restrict__ W,
    const float* __restrict__ a,
    unsigned short* __restrict__ Xh, unsigned short* __restrict__ WbT,
    unsigned* __restrict__ adjbitsT, unsigned short* __restrict__ WAh) {
  int bid = blockIdx.x, tid = threadIdx.x;
  if (bid < 2048) {                       // adj -> bit words, transposed [jt][r]
    int item = bid * 256 + tid;           // item = jt*4096 + r
    int jt = item >> 12, r = item & 4095;
    const int* p = adj + (size_t)r * NN + jt * 32;
    unsigned bits = 0;
#pragma unroll
    for (int b = 0; b < 32; b += 4) {
      int4 v = *(const int4*)(p + b);
      bits |= (unsigned)(v.x & 1) << b;
      bits |= (unsigned)(v.y & 1) << (b + 1);
      bits |= (unsigned)(v.z & 1) << (b + 2);
      bits |= (unsigned)(v.w & 1) << (b + 3);
    }
    adjbitsT[item] = bits;
  } else if (bid < 4096) {                // X -> fp16
    int item = (bid - 2048) * 256 + tid;
    float4 v = ((const float4*)X)[item];
    ushort4 o;
    o.x = f2h(v.x); o.y = f2h(v.y); o.z = f2h(v.z); o.w = f2h(v.w);
    ((ushort4*)Xh)[item] = o;
  } else if (bid < 5120) {                // W[h][k][o] -> WbT[h][o][k] fp16
    int item = (bid - 4096) * 256 + tid;
    int h = item >> 15, rem = item & 32767, o = rem >> 9, k = rem & 511;
    WbT[item] = f2h(W[h * (FIN * FO) + k * FO + o]);
  } else {                                // wa[t][k] = sum_o W[h][k][o] * a[h][which*64+o]
    int item = (bid - 5120) * 256 + tid;  // 8192 items: t = h*2+which, k
    int h = item >> 10, which = (item >> 9) & 1, k = item & 511;
    const float4* wp = (const float4*)(W + ((size_t)h * FIN + k) * FO);
    const float4* ap = (const float4*)(a + h * 128 + which * 64);
    float s = 0.f;
#pragma unroll
    for (int o4 = 0; o4 < 16; ++o4) {
      float4 w4 = wp[o4], a4 = ap[o4];
      s += w4.x * a4.x + w4.y * a4.y + w4.z * a4.z + w4.w * a4.w;
    }
    WAh[(h * 2 + which) * FIN + k] = f2h(s);
  }
}

// ---------------- proj (+sd): Wh fragments fp16, s,d -> AB / E1h,E2h tables ---------
// D layout (16x16x32): col = lane&15, row = (lane>>4)*4 + reg   [m89]
__global__ __launch_bounds__(256, 4) void proj_sd_kernel(
    const unsigned short* __restrict__ Xh, const unsigned short* __restrict__ WbT,
    const unsigned short* __restrict__ WAh,
    unsigned short* __restrict__ Whfrag, float2* __restrict__ ABf,
    unsigned short* __restrict__ E1h, unsigned short* __restrict__ E2h) {
  int lane = threadIdx.x & 63, wave = threadIdx.x >> 6;
  int row16 = lane & 15, grp = lane >> 4;
  if (blockIdx.y == 8) {                  // sd: [s,d]x8 = X @ WA  (16 cols, K=512)
    int i0 = (blockIdx.x * 4 + wave) * 16;
    f32x4 acc = {0, 0, 0, 0};
    const unsigned short* xb = Xh + (size_t)(i0 + row16) * FIN + grp * 8;
    const unsigned short* wb = WAh + row16 * FIN + grp * 8;
#pragma unroll
    for (int k0 = 0; k0 < FIN; k0 += 32)
      acc = __builtin_amdgcn_mfma_f32_16x16x32_f16(*(const f16x8*)(xb + k0),
                                                   *(const f16x8*)(wb + k0), acc, 0, 0, 0);
    int hh = row16 >> 1;
#pragma unroll
    for (int reg = 0; reg < 4; ++reg) {
      int rr = i0 + grp * 4 + reg;
      float v = acc[reg];
      if (row16 & 1) {                    // d -> col tables fp16
        E1h[hh * NN + rr] = f2h(__expf(v));
        E2h[hh * NN + rr] = f2h(__expf(0.2f * v));
      } else {                            // s -> row tables f32
        ABf[hh * NN + rr] = make_float2(__expf(v), __expf(0.2f * v));
      }
    }
    return;
  }
  int h = blockIdx.y;
  int i0 = blockIdx.x * 64 + wave * 16;
  f32x4 acc[4] = {{0,0,0,0},{0,0,0,0},{0,0,0,0},{0,0,0,0}};
  const unsigned short* xb = Xh + (size_t)(i0 + row16) * FIN + grp * 8;
  const unsigned short* wb = WbT + h * (FO * FIN) + row16 * FIN + grp * 8;
#pragma unroll 4
  for (int k0 = 0; k0 < FIN; k0 += 32) {
    f16x8 af = *(const f16x8*)(xb + k0);
#pragma unroll
    for (int cb = 0; cb < 4; ++cb)
      acc[cb] = __builtin_amdgcn_mfma_f32_16x16x32_f16(
          af, *(const f16x8*)(wb + cb * 16 * FIN + k0), acc[cb], 0, 0, 0);
  }
  // Whfrag[h][jt][cb][l][e] = Wh[jt*32 + (l>>4)*8 + e][cb*16 + (l&15)]
  int jt = i0 >> 5;
  int kk0 = (i0 & 31) + grp * 4;
  int tl = (kk0 >> 3) * 16 + row16;
  int e0 = kk0 & 7;
#pragma unroll
  for (int cb = 0; cb < 4; ++cb) {
    ushort4 pk;
    pk.x = f2h(acc[cb][0]); pk.y = f2h(acc[cb][1]);
    pk.z = f2h(acc[cb][2]); pk.w = f2h(acc[cb][3]);
    *(ushort4*)(Whfrag + (((size_t)h * 128 + jt) * 4 + cb) * 512 + tl * 8 + e0) = pk;
  }
}

// ---------------- gat: 2-phase LDS pipeline, PH=2, 4 rt x 2 jseg, 36KB LDS ---------
// SEG layout: [B: 2 tiles x 4096 | E1: 2x64x2B | E2: 2x64x2B | adj: 2x256] = 8960 -> 9216
#define SEGB 9216
#define E_OFF 8192
#define A_OFF 8448
#define PH 2
#define NPHASE 32

__global__ __launch_bounds__(512, 8) void gat_kernel(
    const unsigned* __restrict__ adjbitsT, const unsigned short* __restrict__ Whfrag,
    const float2* __restrict__ ABf, const unsigned short* __restrict__ E1h,
    const unsigned short* __restrict__ E2h, float* __restrict__ out) {
  __shared__ __align__(16) char lds[4 * SEGB];
  int h = blockIdx.y;
  int lane = threadIdx.x & 63, wave = threadIdx.x >> 6;
  int row16 = lane & 15, grp = lane >> 4;
  int rt = wave >> 1, jseg = wave & 1;
  int r0 = blockIdx.x * 64;
  int i0 = r0 + rt * 16;
  int r = i0 + row16;
  float2 ab = ABf[h * NN + r];
  _Float16 Ah1 = (_Float16)(0.5f * ab.x);   // pre-halved: mask supplies x2
  _Float16 Bh1 = (_Float16)(0.5f * ab.y);
  f16x2 Ah = {Ah1, Ah1}, Bh = {Bh1, Bh1};

  H8 ones;
#pragma unroll
  for (int k = 0; k < 4; ++k) ones.u[k] = 0x3C003C00u;   // fp16 1.0 pairs

  const unsigned short* wsrc = Whfrag + (size_t)h * 262144 + lane * 8;
  const unsigned short* e1src = E1h + h * NN + jseg * 2048 + lane * 8;
  const unsigned short* e2src = E2h + h * NN + jseg * 2048 + lane * 8;

  f32x4 a0 = {0,0,0,0}, a1 = {0,0,0,0}, a2 = {0,0,0,0}, ad = {0,0,0,0}, aden = {0,0,0,0};

  // ---- stage phase p into buffer buf ----
  auto stage = [&](int buf, int p) {
    char* base = lds + (jseg * 2 + buf) * SEGB;
    int jt0 = jseg * 64 + p * PH;
    if (rt < 2) {                          // B-frags: wave rt stages tile rt (4KB)
      const unsigned short* bs = wsrc + (size_t)(jt0 + rt) * 2048;
      char* bd = base + rt * 4096;
      GLOAD_LDS16(bs, bd);
      GLOAD_LDS16(bs + 512, bd + 1024);
      GLOAD_LDS16(bs + 1024, bd + 2048);
      GLOAD_LDS16(bs + 1536, bd + 3072);
    } else {                               // adj + E tables
      int t = rt - 2;
      GLOAD_LDS4(adjbitsT + (size_t)(jt0 + t) * NN + r0 + lane, base + A_OFF + t * 256);
      if (lane < 8) {
        const unsigned short* es = (t == 0 ? e1src : e2src) + p * (PH * 32);
        GLOAD_LDS16(es, base + E_OFF + t * 128);
      }
    }
  };

  // ---- compute one phase from buffer buf ----
  auto compute = [&](int buf) {
    char* base = lds + (jseg * 2 + buf) * SEGB;
#pragma unroll
    for (int t = 0; t < PH; ++t) {
      unsigned bw = *(const unsigned*)(base + A_OFF + t * 256 + (rt * 16 + row16) * 4);
      unsigned bb = (bw >> (grp * 8)) & 0xffu;
      H8 e1, e2;
      e1.v = *(const f16x8*)(base + E_OFF + t * 64 + grp * 16);
      e2.v = *(const f16x8*)(base + E_OFF + 128 + t * 64 + grp * 16);
      const char* bbase = base + t * 4096 + lane * 16;
      f16x8 b0 = *(const f16x8*)(bbase);
      f16x8 b1 = *(const f16x8*)(bbase + 1024);
      f16x8 b2 = *(const f16x8*)(bbase + 2048);
      f16x8 b3 = *(const f16x8*)(bbase + 3072);
      H8 af;
#pragma unroll
      for (int k = 0; k < 4; ++k) {
        f16x2 mx = __builtin_elementwise_max(Ah * e1.p[k], Bh * e2.p[k]);
        U2 m;                              // mask halves: bit<<14 = fp16 2.0 (or 0)
        m.u = (((bb >> (2 * k)) & 1u) << 14) | (((bb >> (2 * k + 1)) & 1u) << 30);
        af.p[k] = mx * m.v;
      }
      a0   = __builtin_amdgcn_mfma_f32_16x16x32_f16(af.v, b0, a0, 0, 0, 0);
      a1   = __builtin_amdgcn_mfma_f32_16x16x32_f16(af.v, b1, a1, 0, 0, 0);
      a2   = __builtin_amdgcn_mfma_f32_16x16x32_f16(af.v, b2, a2, 0, 0, 0);
      aden = __builtin_amdgcn_mfma_f32_16x16x32_f16(af.v, ones.v, aden, 0, 0, 0);
      ad   = __builtin_amdgcn_mfma_f32_16x16x32_f16(af.v, b3, ad, 0, 0, 0);
    }
  };

  stage(0, 0);
  __syncthreads();                       // drains vmcnt -> phase 0 ready
  int b = 0;
#pragma unroll 1
  for (int p = 0; p < NPHASE; ++p) {
    if (p < NPHASE - 1) stage(b ^ 1, p + 1);   // async into other buffer
    compute(b);
    __syncthreads();                     // staged loads landed under compute
    b ^= 1;
  }

  // ---- cross-jseg reduction (reuse LDS) + normalize + store ----
  float* red = (float*)lds;
  if (jseg == 1) {
    float* q = red + (rt * 64 + lane) * 20;
    *(f32x4*)(q +  0) = a0;
    *(f32x4*)(q +  4) = a1;
    *(f32x4*)(q +  8) = a2;
    *(f32x4*)(q + 12) = ad;
    *(f32x4*)(q + 16) = aden;
  }
  __syncthreads();
  if (jseg == 0) {
    const float* q = red + (rt * 64 + lane) * 20;
    a0   += *(const f32x4*)(q +  0);
    a1   += *(const f32x4*)(q +  4);
    a2   += *(const f32x4*)(q +  8);
    ad   += *(const f32x4*)(q + 12);
    aden += *(const f32x4*)(q + 16);
#pragma unroll
    for (int reg = 0; reg < 4; ++reg) {
      float inv = 1.0f / aden[reg];
      int row = i0 + grp * 4 + reg;
      float* op = out + (size_t)row * (NH * FO) + h * FO + row16;
      op[0]  = a0[reg] * inv;
      op[16] = a1[reg] * inv;
      op[32] = a2[reg] * inv;
      op[48] = ad[reg] * inv;
    }
  }
}

extern "C" void kernel_launch(void* const* d_in, const int* in_sizes, int n_in,
                              void* d_out, int out_size, void* d_ws, size_t ws_size,
                              hipStream_t stream) {
  const float* X  = (const float*)d_in[0];
  const int* adj  = (const int*)d_in[1];
  const float* W  = (const float*)d_in[2];
  const float* a  = (const float*)d_in[3];
  float* out = (float*)d_out;
  char* ws = (char*)d_ws;

  unsigned short* Xh     = (unsigned short*)(ws + 0);          // 4 MB
  unsigned short* WbT    = (unsigned short*)(ws + 4194304);    // 512 KB
  unsigned* adjbitsT     = (unsigned*)(ws + 4718592);          // 2 MB
  unsigned short* Whfrag = (unsigned short*)(ws + 6815744);    // 4 MB
  unsigned short* WAh    = (unsigned short*)(ws + 11010048);   // 16 KB
  float2* ABf            = (float2*)(ws + 11026432);           // 256 KB
  unsigned short* E1h    = (unsigned short*)(ws + 11288576);   // 64 KB
  unsigned short* E2h    = (unsigned short*)(ws + 11354112);   // 64 KB (total ~11.4 MB)

  prep_kernel<<<5152, 256, 0, stream>>>(X, adj, W, a, Xh, WbT, adjbitsT, WAh);
  proj_sd_kernel<<<dim3(64, 9), 256, 0, stream>>>(Xh, WbT, WAh, Whfrag, ABf, E1h, E2h);
  gat_kernel<<<dim3(64, 8), 512, 0, stream>>>(adjbitsT, Whfrag, ABf, E1h, E2h, out);
}